// Round 6
// baseline (960.040 us; speedup 1.0000x reference)
//
#include <hip/hip_runtime.h>
#include <hip/hip_bf16.h>
#include <cstdint>
#include <cstddef>

#define B_ 2
#define T_ 1024
#define D_ 2048
#define H_ 16
#define DK_ 128
#define DV_ 128
#define ROWS (B_*T_)      // 2048
// Y columns: [q 0:2048 | k 2048:4096 | v 4096:6144 | a 6144:8192 | g 8192:10240 | beta 10240:10256 | pad :10368]
#define NCAT 10368
#define YSTRIDE 10368
#define NGRP 256          // T/4 groups of 4 steps

typedef __attribute__((ext_vector_type(8))) short bf16x8;
typedef __attribute__((ext_vector_type(4))) float f32x4;

__device__ inline unsigned short f2bf(float f){
    union { float f; unsigned int u; } v; v.f = f;
    unsigned int r = (v.u + 0x7fffu + ((v.u >> 16) & 1u)) >> 16;
    return (unsigned short)r;
}
__device__ inline float sigm(float x){ return 1.0f / (1.0f + __expf(-x)); }

// ---- DPP helpers ----
template<int CTRL>
__device__ __forceinline__ float dpp_add(float x){
    int t = __builtin_amdgcn_update_dpp(0, __builtin_bit_cast(int, x), CTRL, 0xf, 0xf, true);
    return x + __builtin_bit_cast(float, t);
}
__device__ __forceinline__ float rl63(float x){
    return __builtin_bit_cast(float, __builtin_amdgcn_readlane(__builtin_bit_cast(int, x), 63));
}
__device__ __forceinline__ const float* rflp(const float* p){
    uint64_t u = (uint64_t)p;
    uint32_t lo = __builtin_amdgcn_readfirstlane((uint32_t)(u & 0xffffffffu));
    uint32_t hi = __builtin_amdgcn_readfirstlane((uint32_t)(u >> 32));
    return (const float*)((((uint64_t)hi) << 32) | lo);
}
__device__ __forceinline__ void gl2lds16(const void* g, void* l){
    __builtin_amdgcn_global_load_lds((const __attribute__((address_space(1))) void*)g,
                                     (__attribute__((address_space(3))) void*)l, 16, 0, 0);
}
__device__ __forceinline__ float dot2(float2 a, float2 b){ return fmaf(a.x, b.x, a.y*b.y); }

// ---------------- fused fp32 -> bf16 casts (one launch) ----------------
struct Cast8 { const float* p[8]; };  // x, Wq, Wk, Wv, Wa, Wg, Wo, Wb
__global__ void cast_all_kernel(Cast8 args, unsigned short* __restrict__ xb,
                                unsigned short* __restrict__ Wcat,
                                unsigned short* __restrict__ Wob){
    int blk = blockIdx.x;
    if (blk >= 28704) {  // zero-pad rows 10256..10367 of Wcat
        int i = (blk - 28704)*1024 + threadIdx.x*4;
        *(ushort4*)(Wcat + (size_t)10256*2048 + i) = (ushort4){0,0,0,0};
        return;
    }
    const float* src; unsigned short* dst; int i;
    if (blk >= 28672) {  // Wb -> Wcat rows 10240..10255
        i = (blk - 28672)*1024 + threadIdx.x*4;
        src = args.p[7]; dst = Wcat + (size_t)10240*2048;
    } else {
        int seg = blk >> 12;
        i = (blk & 4095)*1024 + threadIdx.x*4;
        src = args.p[seg];
        if (seg == 0)      dst = xb;
        else if (seg <= 5) dst = Wcat + (size_t)(seg-1)*4194304;
        else               dst = Wob;
    }
    float4 f = *(const float4*)(src + i);
    ushort4 u; u.x = f2bf(f.x); u.y = f2bf(f.y); u.z = f2bf(f.z); u.w = f2bf(f.w);
    *(ushort4*)(dst + i) = u;
}

// ---------------- bf16 GEMM (m97-style): C[M,N] = A[M,K]*Bm[N,K]^T ----------------
__global__ __launch_bounds__(256) void gemm_bt(
    const unsigned short* __restrict__ A,
    const unsigned short* __restrict__ Bm,
    float* __restrict__ C, int M, int N, int K,
    int act_start, const float* __restrict__ ba, const float* __restrict__ bbeta)
{
    __shared__ __align__(16) unsigned short lA[128*32];
    __shared__ __align__(16) unsigned short lB[128*32];
    const int tid  = threadIdx.x;
    const int wave = tid >> 6, lane = tid & 63;
    const int quad = lane >> 4, l16 = lane & 15;
    const int wm = wave >> 1, wn = wave & 1;
    const int m0 = blockIdx.y * 128, n0 = blockIdx.x * 128;

    const unsigned short* gsrcA[2];
    const unsigned short* gsrcB[2];
    unsigned short* ldst[2];
    #pragma unroll
    for (int i = 0; i < 2; i++) {
        int chunk = wave*128 + i*64 + lane;
        int r = chunk >> 2, p = chunk & 3;
        int gcb = p ^ (r & 3);
        gsrcA[i] = A  + (size_t)(m0 + r)*K + gcb*8;
        gsrcB[i] = Bm + (size_t)(n0 + r)*K + gcb*8;
        ldst[i]  = (unsigned short*)((char*)lA + (size_t)(wave*128 + i*64)*16);
    }
    const size_t lBoff = (size_t)((char*)lB - (char*)lA);

    f32x4 acc[4][4];
    #pragma unroll
    for (int i = 0; i < 4; i++)
        #pragma unroll
        for (int j = 0; j < 4; j++) acc[i][j] = (f32x4){0.f,0.f,0.f,0.f};

    for (int k0 = 0; k0 < K; k0 += 32) {
        __syncthreads();
        #pragma unroll
        for (int i = 0; i < 2; i++) {
            gl2lds16(gsrcA[i] + k0, ldst[i]);
            gl2lds16(gsrcB[i] + k0, (char*)ldst[i] + lBoff);
        }
        __syncthreads();
        bf16x8 af[4], bfr[4];
        #pragma unroll
        for (int i = 0; i < 4; i++) {
            int ra = wm*64 + i*16 + l16;
            int rb = wn*64 + i*16 + l16;
            af[i]  = *(const bf16x8*)(&lA[ra*32 + ((quad ^ (ra & 3))*8)]);
            bfr[i] = *(const bf16x8*)(&lB[rb*32 + ((quad ^ (rb & 3))*8)]);
        }
        #pragma unroll
        for (int i = 0; i < 4; i++)
            #pragma unroll
            for (int j = 0; j < 4; j++)
                acc[i][j] = __builtin_amdgcn_mfma_f32_16x16x32_bf16(af[i], bfr[j], acc[i][j], 0, 0, 0);
    }

    #pragma unroll
    for (int i = 0; i < 4; i++) {
        int m = m0 + wm*64 + i*16 + quad*4;
        #pragma unroll
        for (int j = 0; j < 4; j++) {
            int n = n0 + wn*64 + j*16 + l16;
            #pragma unroll
            for (int r = 0; r < 4; r++) {
                float y = acc[i][j][r];
                if (n >= act_start) {
                    float bsum = 0.0f;
                    if (n < 8192) bsum = ba[n - 6144];
                    else if (n >= 10240 && n < 10256) bsum = bbeta[n - 10240];
                    y = sigm(y + bsum);
                }
                C[(size_t)(m + r)*N + n] = y;
            }
        }
    }
}

// ---------------- causal depthwise conv (K=4) + silu + scale, [b,t,c] out ----------------
__global__ void conv_silu_kernel(const float* __restrict__ Y, int col_off,
                                 const float* __restrict__ cw, const float* __restrict__ cb,
                                 float scale, float* __restrict__ out)
{
    int gid = blockIdx.x * blockDim.x + threadIdx.x;  // 32768 total
    int c = gid & 2047;
    int tmp = gid >> 11;
    int tch = tmp & 7;
    int b = tmp >> 3;
    int t0 = tch * 128;
    const float w0 = cw[c*4+0], w1 = cw[c*4+1], w2 = cw[c*4+2], w3 = cw[c*4+3];
    const float bias = cb[c];
    const float* src = Y + (size_t)b*T_*YSTRIDE + col_off + c;
    float* dst = out + (size_t)b*T_*2048 + c;
    float y0 = (t0 >= 3) ? src[(size_t)(t0-3)*YSTRIDE] : 0.f;
    float y1 = (t0 >= 2) ? src[(size_t)(t0-2)*YSTRIDE] : 0.f;
    float y2 = (t0 >= 1) ? src[(size_t)(t0-1)*YSTRIDE] : 0.f;
    for (int t = t0; t < t0 + 128; t++) {
        float y3 = src[(size_t)t*YSTRIDE];
        float s = fmaf(w0,y0, fmaf(w1,y1, fmaf(w2,y2, fmaf(w3,y3, bias))));
        float r = s * (1.0f/(1.0f + __expf(-s))) * scale;
        dst[(size_t)t*2048] = r;
        y0 = y1; y1 = y2; y2 = y3;
    }
}

// ---------------- same conv but writes TRANSPOSED [b,c,t] (for v), float4-buffered ----------------
__global__ void conv_silu_T_kernel(const float* __restrict__ Y, int col_off,
                                   const float* __restrict__ cw, const float* __restrict__ cb,
                                   float* __restrict__ out)
{
    int gid = blockIdx.x * blockDim.x + threadIdx.x;
    int c = gid & 2047;
    int tmp = gid >> 11;
    int tch = tmp & 7;
    int b = tmp >> 3;
    int t0 = tch * 128;
    const float w0 = cw[c*4+0], w1 = cw[c*4+1], w2 = cw[c*4+2], w3 = cw[c*4+3];
    const float bias = cb[c];
    const float* src = Y + (size_t)b*T_*YSTRIDE + col_off + c;
    float* dst = out + ((size_t)b*2048 + c)*1024;
    float y0 = (t0 >= 3) ? src[(size_t)(t0-3)*YSTRIDE] : 0.f;
    float y1 = (t0 >= 2) ? src[(size_t)(t0-2)*YSTRIDE] : 0.f;
    float y2 = (t0 >= 1) ? src[(size_t)(t0-1)*YSTRIDE] : 0.f;
    for (int t = t0; t < t0 + 128; t += 4) {
        float4 r;
        #pragma unroll
        for (int jj = 0; jj < 4; jj++) {
            float y3 = src[(size_t)(t+jj)*YSTRIDE];
            float s = fmaf(w0,y0, fmaf(w1,y1, fmaf(w2,y2, fmaf(w3,y3, bias))));
            ((float*)&r)[jj] = s * (1.0f/(1.0f + __expf(-s)));
            y0 = y1; y1 = y2; y2 = y3;
        }
        *(float4*)(dst + t) = r;
    }
}

// ---------------- [T x C] -> [C x T] transpose (for a) ----------------
__global__ __launch_bounds__(256) void transpose_kernel(const float* __restrict__ src, int srcStride,
                                                        float* __restrict__ dst, int C)
{
    __shared__ float tile[64][65];
    int tblk = blockIdx.x*64, cblk = blockIdx.y*64, b = blockIdx.z;
    int tx = threadIdx.x & 63, ty4 = threadIdx.x >> 6;
    const float* s = src + (size_t)b*T_*srcStride;
    #pragma unroll
    for (int i = 0; i < 16; i++) {
        int t = ty4*16 + i;
        tile[t][tx] = s[(size_t)(tblk + t)*srcStride + cblk + tx];
    }
    __syncthreads();
    float* d = dst + (size_t)b*C*1024;
    #pragma unroll
    for (int i = 0; i < 16; i++) {
        int cc = ty4*16 + i;
        d[(size_t)(cblk + cc)*1024 + tblk + tx] = tile[tx][cc];
    }
}

// ---------------- beta -> [b,h,t] ----------------
__global__ void bpack_kernel(const float* __restrict__ Y, float* __restrict__ bpack){
    int blk = blockIdx.x;              // b*16+h
    int b = blk >> 4, h = blk & 15;
    for (int t = threadIdx.x; t < 1024; t += 256)
        bpack[(size_t)blk*1024 + t] = Y[((size_t)b*T_ + t)*YSTRIDE + 10240 + h];
}

// ---------------- gram precompute: per (b,h,group): 16 k/q dot scalars ----------------
// layout [kk12,kk13,kk14,kk23,kk24,kk34, kq11,kq12,kq13,kq14, kq22,kq23,kq24, kq33,kq34, kq44]
__global__ __launch_bounds__(256) void gram_kernel(const float* __restrict__ qs,
                                                   const float* __restrict__ ks,
                                                   float* __restrict__ gram)
{
    int wid = blockIdx.x*4 + (threadIdx.x >> 6);   // 0..8191
    int lane = threadIdx.x & 63;
    int g = wid & 255, bh = wid >> 8;
    int b = bh >> 4, h = bh & 15;
    const float2* kb = (const float2*)(ks + ((size_t)b*T_ + g*4)*2048 + h*128) + lane;
    const float2* qb = (const float2*)(qs + ((size_t)b*T_ + g*4)*2048 + h*128) + lane;
    float2 k1 = kb[0], k2 = kb[1024], k3 = kb[2048], k4 = kb[3072];
    float2 q1 = qb[0], q2 = qb[1024], q3 = qb[2048], q4 = qb[3072];
    float p[16];
    p[0]=dot2(k1,k2); p[1]=dot2(k1,k3); p[2]=dot2(k1,k4); p[3]=dot2(k2,k3);
    p[4]=dot2(k2,k4); p[5]=dot2(k3,k4);
    p[6]=dot2(k1,q1); p[7]=dot2(k1,q2); p[8]=dot2(k1,q3); p[9]=dot2(k1,q4);
    p[10]=dot2(k2,q2); p[11]=dot2(k2,q3); p[12]=dot2(k2,q4);
    p[13]=dot2(k3,q3); p[14]=dot2(k3,q4); p[15]=dot2(k4,q4);
    #pragma unroll
    for (int i=0;i<16;i++) p[i]=dpp_add<0x111>(p[i]);
    #pragma unroll
    for (int i=0;i<16;i++) p[i]=dpp_add<0x112>(p[i]);
    #pragma unroll
    for (int i=0;i<16;i++) p[i]=dpp_add<0x114>(p[i]);
    #pragma unroll
    for (int i=0;i<16;i++) p[i]=dpp_add<0x118>(p[i]);
    #pragma unroll
    for (int i=0;i<16;i++) p[i]=dpp_add<0x142>(p[i]);
    #pragma unroll
    for (int i=0;i<16;i++) p[i]=dpp_add<0x143>(p[i]);
    // readlane -> SGPRs (uniform across wave); lane 0 stores 4x float4
    float v0=rl63(p[0]),  v1=rl63(p[1]),  v2=rl63(p[2]),  v3=rl63(p[3]);
    float v4=rl63(p[4]),  v5=rl63(p[5]),  v6=rl63(p[6]),  v7=rl63(p[7]);
    float v8=rl63(p[8]),  v9=rl63(p[9]),  v10=rl63(p[10]), v11=rl63(p[11]);
    float v12=rl63(p[12]), v13=rl63(p[13]), v14=rl63(p[14]), v15=rl63(p[15]);
    if (lane == 0) {
        float4* gout = (float4*)(gram + ((size_t)bh*NGRP + g)*16);
        gout[0] = (float4){v0,v1,v2,v3};
        gout[1] = (float4){v4,v5,v6,v7};
        gout[2] = (float4){v8,v9,v10,v11};
        gout[3] = (float4){v12,v13,v14,v15};
    }
}

// ---------------- gated delta recurrence: 4-step grouped, 1 v-row per wave ----------------
struct SBk { float4 av, vv, bv, g0, g1, g2, g3; };

__device__ __forceinline__ SBk load_sb(const float* ap, const float* vp, const float* bp,
                                       const float4* gp, int g){
    SBk r;
    r.av = *(const float4*)(ap + g*4);
    r.vv = *(const float4*)(vp + g*4);
    r.bv = *(const float4*)(bp + g*4);
    r.g0 = gp[g*4+0]; r.g1 = gp[g*4+1]; r.g2 = gp[g*4+2]; r.g3 = gp[g*4+3];
    return r;
}

#define GROUP4(KV, QV, SBv, t0) { \
    float pr[8]; \
    pr[0]=dot2(s,KV[0]); pr[1]=dot2(s,KV[1]); pr[2]=dot2(s,KV[2]); pr[3]=dot2(s,KV[3]); \
    pr[4]=dot2(s,QV[0]); pr[5]=dot2(s,QV[1]); pr[6]=dot2(s,QV[2]); pr[7]=dot2(s,QV[3]); \
    _Pragma("unroll") for (int i_=0;i_<8;i_++) pr[i_]=dpp_add<0x111>(pr[i_]); \
    _Pragma("unroll") for (int i_=0;i_<8;i_++) pr[i_]=dpp_add<0x112>(pr[i_]); \
    _Pragma("unroll") for (int i_=0;i_<8;i_++) pr[i_]=dpp_add<0x114>(pr[i_]); \
    _Pragma("unroll") for (int i_=0;i_<8;i_++) pr[i_]=dpp_add<0x118>(pr[i_]); \
    _Pragma("unroll") for (int i_=0;i_<8;i_++) pr[i_]=dpp_add<0x142>(pr[i_]); \
    _Pragma("unroll") for (int i_=0;i_<8;i_++) pr[i_]=dpp_add<0x143>(pr[i_]); \
    float sk1=rl63(pr[0]), sk2=rl63(pr[1]), sk3=rl63(pr[2]), sk4=rl63(pr[3]); \
    float sq1=rl63(pr[4]), sq2=rl63(pr[5]), sq3=rl63(pr[6]), sq4=rl63(pr[7]); \
    const float a1=SBv.av.x, a2=SBv.av.y, a3=SBv.av.z, a4=SBv.av.w; \
    float u1 = SBv.bv.x*(sk1 - SBv.vv.x); \
    float e2   = fmaf(a1, sk2, -(u1*SBv.g0.x)); \
    float pre3 = fmaf(a1, sk3, -(u1*SBv.g0.y)); \
    float pre4 = fmaf(a1, sk4, -(u1*SBv.g0.z)); \
    float u2 = SBv.bv.y*(e2 - SBv.vv.y); \
    float e3    = fmaf(a2, pre3, -(u2*SBv.g0.w)); \
    float pre4b = fmaf(a2, pre4, -(u2*SBv.g1.x)); \
    float u3 = SBv.bv.z*(e3 - SBv.vv.z); \
    float e4 = fmaf(a3, pre4b, -(u3*SBv.g1.y)); \
    float u4 = SBv.bv.w*(e4 - SBv.vv.w); \
    float o1 = fmaf(a1, sq1, -(u1*SBv.g1.z)); \
    float t2_ = fmaf(a1, sq2, -(u1*SBv.g1.w)); \
    float o2 = fmaf(a2, t2_, -(u2*SBv.g2.z)); \
    float t3_ = fmaf(a1, sq3, -(u1*SBv.g2.x)); \
    float t3b = fmaf(a2, t3_, -(u2*SBv.g2.w)); \
    float o3 = fmaf(a3, t3b, -(u3*SBv.g3.y)); \
    float t4_ = fmaf(a1, sq4, -(u1*SBv.g2.y)); \
    float t4b = fmaf(a2, t4_, -(u2*SBv.g3.x)); \
    float t4c = fmaf(a3, t4b, -(u3*SBv.g3.z)); \
    float o4 = fmaf(a4, t4c, -(u4*SBv.g3.w)); \
    if (lane == 0) { \
        op[(size_t)(t0)*2048]   = o1; op[(size_t)((t0)+1)*2048] = o2; \
        op[(size_t)((t0)+2)*2048] = o3; op[(size_t)((t0)+3)*2048] = o4; } \
    float pB = a3*a4; \
    float c1 = u1*(a2*pB), c2 = u2*pB, c3 = u3*a4; \
    float ptot = (a1*a2)*pB; \
    float nx = ptot*s.x; \
    nx = fmaf(-c1, KV[0].x, nx); nx = fmaf(-c2, KV[1].x, nx); \
    nx = fmaf(-c3, KV[2].x, nx); nx = fmaf(-u4, KV[3].x, nx); \
    float ny = ptot*s.y; \
    ny = fmaf(-c1, KV[0].y, ny); ny = fmaf(-c2, KV[1].y, ny); \
    ny = fmaf(-c3, KV[2].y, ny); ny = fmaf(-u4, KV[3].y, ny); \
    s.x = nx; s.y = ny; \
}

__global__ __launch_bounds__(256) void recurrence_kernel(
    const float* __restrict__ q, const float* __restrict__ k,      // [b][t][2048]
    const float* __restrict__ apack, const float* __restrict__ vpack, // [b][c][t]
    const float* __restrict__ bpack,  // [b][h][t]
    const float* __restrict__ gram,   // [b*16+h][g][16]
    float* __restrict__ o)            // [b][t][2048]
{
    const int blk = blockIdx.x;       // rowgrp*32 + bh
    const int bh = blk & 31;
    const int rowgrp = blk >> 5;
    const int h = bh & 15, b = bh >> 4;
    const int lane = threadIdx.x & 63;
    const int wave = __builtin_amdgcn_readfirstlane(threadIdx.x >> 6);
    const int vrow = rowgrp*4 + wave;
    const int c = h*128 + vrow;

    const float*  ap = rflp(apack + ((size_t)b*2048 + c)*1024);
    const float*  vp = rflp(vpack + ((size_t)b*2048 + c)*1024);
    const float*  bp = rflp(bpack + (size_t)bh*1024);
    const float4* gp = (const float4*)rflp(gram + (size_t)bh*NGRP*16);
    const float2* kp = (const float2*)rflp(k + (size_t)b*T_*2048 + h*128) + lane;
    const float2* qp = (const float2*)rflp(q + (size_t)b*T_*2048 + h*128) + lane;
    float* op = o + (size_t)b*T_*2048 + c;

    float2 s = {0.f, 0.f};
    float2 kA[4], qA[4], kB[4], qB[4];

    #pragma unroll
    for (int j = 0; j < 4; j++) { kA[j] = kp[j*1024]; qA[j] = qp[j*1024]; }
    SBk sA = load_sb(ap, vp, bp, gp, 0), sB;

    #pragma unroll 1
    for (int g = 0; g < NGRP; g += 2) {
        // prefetch group g+1
        #pragma unroll
        for (int j = 0; j < 4; j++) { kB[j] = kp[((g+1)*4+j)*1024]; qB[j] = qp[((g+1)*4+j)*1024]; }
        sB = load_sb(ap, vp, bp, gp, g+1);
        GROUP4(kA, qA, sA, g*4);
        // prefetch group g+2 (final iter overruns into adjacent ws arrays; values unused)
        #pragma unroll
        for (int j = 0; j < 4; j++) { kA[j] = kp[((g+2)*4+j)*1024]; qA[j] = qp[((g+2)*4+j)*1024]; }
        sA = load_sb(ap, vp, bp, gp, g+2);
        GROUP4(kB, qB, sB, (g+1)*4);
    }
}

// ---------------- LayerNorm over DV, * gate, -> bf16 ----------------
__global__ __launch_bounds__(256) void ln_gate_kernel(
    const float* __restrict__ o, const float* __restrict__ g, int g_stride,
    const float* __restrict__ ln_g, const float* __restrict__ ln_b,
    unsigned short* __restrict__ og)
{
    int wave = threadIdx.x >> 6, lane = threadIdx.x & 63;
    int gidx = blockIdx.x*4 + wave;     // 0..32767
    int row = gidx >> 4, h = gidx & 15;
    const float* ob = o + (size_t)row*2048 + h*128;
    int d0 = lane*2;
    float2 xv = *(const float2*)(ob + d0);
    float s = xv.x + xv.y, ss = xv.x*xv.x + xv.y*xv.y;
    for (int m = 1; m < 64; m <<= 1) { s += __shfl_xor(s, m); ss += __shfl_xor(ss, m); }
    float mu  = s * (1.f/128.f);
    float var = ss * (1.f/128.f) - mu*mu;
    float inv = rsqrtf(var + 1e-5f);
    const float* gb = g + (size_t)row*g_stride + h*128;
    float r0 = ((xv.x - mu)*inv*ln_g[d0]   + ln_b[d0])   * gb[d0];
    float r1 = ((xv.y - mu)*inv*ln_g[d0+1] + ln_b[d0+1]) * gb[d0+1];
    ushort2 u; u.x = f2bf(r0); u.y = f2bf(r1);
    *(ushort2*)(og + (size_t)row*2048 + h*128 + d0) = u;
}

extern "C" void kernel_launch(void* const* d_in, const int* in_sizes, int n_in,
                              void* d_out, int out_size, void* d_ws, size_t ws_size,
                              hipStream_t stream)
{
    const float* x   = (const float*)d_in[0];
    const float* Wq  = (const float*)d_in[1];
    const float* Wk  = (const float*)d_in[2];
    const float* Wv  = (const float*)d_in[3];
    const float* Wa  = (const float*)d_in[4];
    const float* ba  = (const float*)d_in[5];
    const float* Wb  = (const float*)d_in[6];
    const float* bb  = (const float*)d_in[7];
    const float* cqw = (const float*)d_in[8];
    const float* cqb = (const float*)d_in[9];
    const float* ckw = (const float*)d_in[10];
    const float* ckb = (const float*)d_in[11];
    const float* cvw = (const float*)d_in[12];
    const float* cvb = (const float*)d_in[13];
    const float* Wg  = (const float*)d_in[14];
    const float* lng = (const float*)d_in[15];
    const float* lnb = (const float*)d_in[16];
    const float* Wo  = (const float*)d_in[17];
    float* out = (float*)d_out;

    char* ws = (char*)d_ws;
    size_t off = 0;
    auto alloc = [&](size_t bytes){ void* p = ws + off; off += (bytes + 255) & ~(size_t)255; return p; };
    unsigned short* xb   = (unsigned short*)alloc((size_t)ROWS*D_*2);   // reused as og
    unsigned short* Wcat = (unsigned short*)alloc((size_t)NCAT*D_*2);   // reused: apack/bpack/gram after proj gemm
    unsigned short* Wob  = (unsigned short*)alloc((size_t)D_*D_*2);
    float* Y     = (float*)alloc((size_t)ROWS*YSTRIDE*4);
    float* qs    = (float*)alloc((size_t)ROWS*2048*4);
    float* ks    = (float*)alloc((size_t)ROWS*2048*4);
    float* vpack = (float*)alloc((size_t)ROWS*2048*4);   // [b][c][t]
    float* ov    = (float*)alloc((size_t)ROWS*2048*4);
    unsigned short* og = xb;
    // carve apack/bpack/gram from the (dead-after-proj-GEMM) Wcat region
    float* apack  = (float*)Wcat;                       // 2*2048*1024 floats
    float* bpackA = apack + (size_t)2*2048*1024;        // 2*16*1024 floats
    float* gramA  = bpackA + (size_t)2*16*1024;         // 32*256*16 floats
    (void)ws_size;

    Cast8 cargs;
    cargs.p[0]=x; cargs.p[1]=Wq; cargs.p[2]=Wk; cargs.p[3]=Wv; cargs.p[4]=Wa;
    cargs.p[5]=Wg; cargs.p[6]=Wo; cargs.p[7]=Wb;
    cast_all_kernel<<<28928, 256, 0, stream>>>(cargs, xb, Wcat, Wob);

    // fused projections + beta: [2048,10368] = xb @ Wcat^T
    gemm_bt<<<dim3(81,16), 256, 0, stream>>>(xb, Wcat, Y, ROWS, NCAT, D_, 6144, ba, bb);

    const float kscale = 0.08838834764831845f;  // DK^-0.5
    conv_silu_kernel  <<<128, 256, 0, stream>>>(Y, 0,    cqw, cqb, 1.0f,   qs);
    conv_silu_kernel  <<<128, 256, 0, stream>>>(Y, 2048, ckw, ckb, kscale, ks);
    conv_silu_T_kernel<<<128, 256, 0, stream>>>(Y, 4096, cvw, cvb, vpack);

    transpose_kernel<<<dim3(16,32,2), 256, 0, stream>>>(Y + 6144, YSTRIDE, apack, 2048);
    bpack_kernel<<<32, 256, 0, stream>>>(Y, bpackA);
    gram_kernel<<<2048, 256, 0, stream>>>(qs, ks, gramA);

    recurrence_kernel<<<1024, 256, 0, stream>>>(qs, ks, apack, vpack, bpackA, gramA, ov);

    ln_gate_kernel<<<8192, 256, 0, stream>>>(ov, Y + 8192, YSTRIDE, lng, lnb, og);

    gemm_bt<<<dim3(16,16), 256, 0, stream>>>(og, Wob, out, ROWS, D_, D_, 1<<30, nullptr, nullptr);
}